// Round 3
// baseline (171.569 us; speedup 1.0000x reference)
//
#include <hip/hip_runtime.h>
#include <math.h>

#define WHN 9216
#define PN 32
#define FN 128
#define BN 8
#define EPSF 1e-8f
#define INV_STD 0.23809523809f   // 1/4.2
#define AUX_IDX 28311552         // 8*128*9216 + 8*128*2*9216

typedef __attribute__((ext_vector_type(8))) short short8;
typedef __attribute__((ext_vector_type(16))) float f32x16;

__device__ __forceinline__ unsigned short f2bf(float x) {
  unsigned int u = __float_as_uint(x);
  unsigned int r = (u + 0x7FFFu + ((u >> 16) & 1u)) >> 16;  // RNE
  return (unsigned short)r;
}
__device__ __forceinline__ float bf2f(unsigned short h) {
  return __uint_as_float(((unsigned int)h) << 16);
}

// ---------------- K1: Gram partials (or atomic fallback) ----------------
// grid (72, 8), block 256. Each block: 128 pixels of one batch.
__global__ __launch_bounds__(256) void k_gram(const float* __restrict__ ms,
                                              float* __restrict__ wsM,
                                              float* __restrict__ wsA,
                                              float* __restrict__ part,
                                              int use_part) {
  const int b = blockIdx.y;
  const int chunk = blockIdx.x;
  const int tid = threadIdx.x;
  __shared__ float4 sA[32][32];
  __shared__ float4 sB[32][32];
  __shared__ float pbuf[2][2048];
  const float4* ms4 = (const float4*)ms;
#pragma unroll
  for (int k = 0; k < 4; ++k) {
    int i4 = tid + k * 256;
    int xq = i4 & 31, p = i4 >> 5;
    sA[xq][p ^ xq] = ms4[((b * 2 + 0) * 32 + p) * 2304 + chunk * 32 + xq];
    sB[xq][p ^ xq] = ms4[((b * 2 + 1) * 32 + p) * 2304 + chunk * 32 + xq];
  }
  __syncthreads();
  const int w = tid >> 6, lane = tid & 63;
  const int pg = lane & 7, qg = lane >> 3;
  float accM[4][4] = {{0}}, accA[4][4] = {{0}};
  for (int xq = w; xq < 32; xq += 4) {
    float4 pa[4], pb[4], qa[4], qb[4];
#pragma unroll
    for (int j = 0; j < 4; ++j) {
      pa[j] = sA[xq][(pg + 8 * j) ^ xq];
      pb[j] = sB[xq][(pg + 8 * j) ^ xq];
      qa[j] = sA[xq][(qg + 8 * j) ^ xq];
      qb[j] = sB[xq][(qg + 8 * j) ^ xq];
    }
#pragma unroll
    for (int j = 0; j < 4; ++j)
#pragma unroll
      for (int k = 0; k < 4; ++k) {
        accM[j][k] += pa[j].x * qa[k].x + pb[j].x * qb[k].x
                    + pa[j].y * qa[k].y + pb[j].y * qb[k].y
                    + pa[j].z * qa[k].z + pb[j].z * qb[k].z
                    + pa[j].w * qa[k].w + pb[j].w * qb[k].w;
        accA[j][k] += pa[j].x * qb[k].x - pb[j].x * qa[k].x
                    + pa[j].y * qb[k].y - pb[j].y * qa[k].y
                    + pa[j].z * qb[k].z - pb[j].z * qa[k].z
                    + pa[j].w * qb[k].w - pb[j].w * qa[k].w;
      }
  }
  if (w < 2) {
#pragma unroll
    for (int j = 0; j < 4; ++j)
#pragma unroll
      for (int k = 0; k < 4; ++k) {
        pbuf[w][lane * 32 + j * 4 + k] = accM[j][k];
        pbuf[w][lane * 32 + 16 + j * 4 + k] = accA[j][k];
      }
  }
  __syncthreads();
  if (w >= 2) {
#pragma unroll
    for (int j = 0; j < 4; ++j)
#pragma unroll
      for (int k = 0; k < 4; ++k) {
        pbuf[w - 2][lane * 32 + j * 4 + k] += accM[j][k];
        pbuf[w - 2][lane * 32 + 16 + j * 4 + k] += accA[j][k];
      }
  }
  __syncthreads();
  for (int idx = tid; idx < 2048; idx += 256) {
    float v = pbuf[0][idx] + pbuf[1][idx];
    if (use_part) {
      part[((size_t)(b * 72 + chunk)) * 2048 + idx] = v;
    } else {
      int lane2 = idx >> 5, r = idx & 31;
      int mat = r >> 4, rr = r & 15, j = rr >> 2, k = rr & 3;
      int p = (lane2 & 7) + 8 * j, q = (lane2 >> 3) + 8 * k;
      float* dst = mat ? wsA : wsM;
      atomicAdd(dst + (b << 10) + p * 32 + q, v);
    }
  }
}

// ---------------- K1b: reduce partials -> M, A, c; zero aux slot ----------------
// grid 64, block 256 (16384 threads = 8 b * 2048 slots)
__global__ __launch_bounds__(256) void k_mid(const float* __restrict__ part,
                                             float* __restrict__ wsM,
                                             float* __restrict__ wsA,
                                             float* __restrict__ wsc,
                                             float* __restrict__ out) {
  int g = blockIdx.x * 256 + threadIdx.x;
  if (g == 0) out[AUX_IDX] = 0.f;
  int b = g >> 11, idx = g & 2047;
  const float* p = part + ((size_t)b * 72) * 2048 + idx;
  float s = 0.f;
#pragma unroll 8
  for (int c = 0; c < 72; ++c) s += p[(size_t)c * 2048];
  int lane2 = idx >> 5, r = idx & 31;
  int mat = r >> 4, rr = r & 15, j = rr >> 2, k = rr & 3;
  int pp = (lane2 & 7) + 8 * j, q = (lane2 >> 3) + 8 * k;
  (mat ? wsA : wsM)[(b << 10) + pp * 32 + q] = s;
  if (!mat && pp == q) wsc[(b << 5) + pp] = (1.0f / 32.0f) / (sqrtf(s) + EPSF);
}

// ---------------- c from M diag (atomic fallback path only) ----------------
__global__ void k_cfromM(const float* __restrict__ wsM, float* __restrict__ wsc,
                         float* __restrict__ out) {
  int tid = threadIdx.x;
  if (tid == 0) out[AUX_IDX] = 0.f;
  int b = tid >> 5, p = tid & 31;
  float m = wsM[(b << 10) + p * 33];
  wsc[tid] = (1.0f / 32.0f) / (sqrtf(m) + EPSF);
}

// ---------------- K2: fnorm + bias (blocks<1024) and aux (blocks>=1024) ----
__global__ __launch_bounds__(64) void k_fnb(const float* __restrict__ t,
                                            const float* __restrict__ freqs,
                                            const float* __restrict__ btab,
                                            const float* __restrict__ wsM,
                                            const float* __restrict__ wsA,
                                            const float* __restrict__ wsc,
                                            float* __restrict__ wsinv,
                                            float* __restrict__ wsbias,
                                            float* __restrict__ out) {
  const int lane = threadIdx.x;
  if (blockIdx.x >= 1024) {
    // aux: one block per batch; lane = (comp, p)
    const int b = blockIdx.x - 1024;
    const int p = lane & 31, comp = lane >> 5;
    float acc = 0.f;
#pragma unroll 4
    for (int f = 0; f < FN; ++f) {
      float v = t[((size_t)(b * FN + f) * 2 + comp) * PN + p];
      acc = fmaf(v, v, acc);
    }
    acc += __shfl_xor(acc, 32);                 // sum comps -> per-p
    float val = logf(sqrtf(acc) + 1.0f);        // same on lane & lane+32
#pragma unroll
    for (int off = 1; off <= 16; off <<= 1) val += __shfl_xor(val, off);
    if (lane == 0) atomicAdd(out + AUX_IDX, val * (1.0f / 256.0f));
    return;
  }
  const int bf = blockIdx.x;
  const int b = bf >> 7;
  __shared__ float tt[64];
  {
    int p = lane & 31, comp = lane >> 5;
    tt[lane] = t[(bf * 2 + comp) * PN + p] * wsc[(b << 5) + p];
  }
  __syncthreads();
  const int pp = lane & 31, qh = lane >> 5;
  const float* Mrow = wsM + (b << 10) + pp * 32 + qh * 16;
  const float* Arow = wsA + (b << 10) + pp * 32 + qh * 16;
  float ap = tt[pp], bp = tt[32 + pp];
  float S = 0.f;
#pragma unroll
  for (int k = 0; k < 16; ++k) {
    int q = qh * 16 + k;
    float aq = tt[q], bq = tt[32 + q];
    S += (ap * aq + bp * bq) * Mrow[k] + 2.0f * (bp * aq) * Arow[k];
  }
#pragma unroll
  for (int off = 32; off; off >>= 1) S += __shfl_xor(S, off);
  if (lane == 0) {
    float fn = sqrtf(fmaxf(S, 1.1920929e-7f));
    wsinv[bf] = 1.0f / fn;
    float x = freqs[bf];
    float idx = (x + 1.0f) * 0.5f * 249.0f;
    idx = fminf(fmaxf(idx, 0.0f), 249.0f);
    float fi = floorf(idx);
    int i0 = (int)fi;
    int i1 = min(i0 + 1, 249);
    float wvv = idx - fi;
    wsbias[bf] = btab[i0] * (1.0f - wvv) + btab[i1] * wvv;
  }
}

// ---------------- K3: main fused pass (split-bf16 MFMA), z-split x2 --------
// grid (72, 8, 2), block 256 = 4 waves; wave -> 32-px strip, 64 f per block.
#define MFMA32(A, B, C) __builtin_amdgcn_mfma_f32_32x32x16_bf16(A, B, C, 0, 0, 0)
__global__ __launch_bounds__(256) void k_main(const float* __restrict__ ms,
                                              const float* __restrict__ t,
                                              const float* __restrict__ wsc,
                                              const float* __restrict__ wsinv,
                                              const float* __restrict__ wsbias,
                                              float* __restrict__ out) {
  __shared__ short tHs[4096];   // [64 f][64 k], k-group XOR-swizzled
  __shared__ short tLs[4096];
  __shared__ float sInv[64], sBias[64], sC[32];
  const int b = blockIdx.y;
  const int tid = threadIdx.x;
  const int lane = tid & 63, wv = tid >> 6;
  const int col = lane & 31, hf = lane >> 5;
  const int pix = blockIdx.x * 128 + wv * 32 + col;
  const int f0 = blockIdx.z * 64;

  // ---- S fragments: raw mode shapes, bf16 hi/lo split (global, no LDS) ----
  const float* msb = ms + (size_t)b * 64 * WHN + pix;
  short8 sHf[4], sLf[4];
#pragma unroll
  for (int kg = 0; kg < 4; ++kg) {
#pragma unroll
    for (int j = 0; j < 8; ++j) {
      int k = kg * 16 + hf * 8 + j;
      float v = msb[(size_t)k * WHN];
      unsigned short h = f2bf(v);
      sHf[kg][j] = (short)h;
      sLf[kg][j] = (short)f2bf(v - bf2f(h));
    }
  }
  short8 msk;
#pragma unroll
  for (int j = 0; j < 8; ++j) msk[j] = (short)0x8000;
  short8 nH2 = sHf[2] ^ msk, nL2 = sLf[2] ^ msk;
  short8 nH3 = sHf[3] ^ msk, nL3 = sLf[3] ^ msk;

  // ---- stage inv/bias/c ----
  if (tid < 64) sInv[tid] = wsinv[b * 128 + f0 + tid];
  else if (tid < 128) sBias[tid - 64] = wsbias[b * 128 + f0 + (tid - 64)];
  if (tid >= 224) sC[tid - 224] = wsc[b * 32 + (tid - 224)];
  __syncthreads();

  // ---- stage T2 = c_p * [t_r ; t_i], hi/lo split, swizzled ----
#pragma unroll
  for (int it = 0; it < 2; ++it) {
    int gidx = tid + it * 256;          // (f_local, k-group)
    int fl = gidx >> 3, g = gidx & 7;
    const float* src = t + ((size_t)(b * 128 + f0 + fl) * 2 + (g >> 2)) * 32 + (g & 3) * 8;
    int gs = g ^ (fl & 7);
    short8 hv, lv;
#pragma unroll
    for (int e = 0; e < 8; ++e) {
      float v = src[e] * sC[(g & 3) * 8 + e];
      unsigned short h = f2bf(v);
      hv[e] = (short)h;
      lv[e] = (short)f2bf(v - bf2f(h));
    }
    *(short8*)&tHs[fl * 64 + gs * 8] = hv;
    *(short8*)&tLs[fl * 64 + gs * 8] = lv;
  }
  __syncthreads();

  float* outF = out + (size_t)BN * FN * WHN;  // normed_field base

#pragma unroll
  for (int ft = 0; ft < 2; ++ft) {
    short8 tHf[4], tLf[4];
    int fl = ft * 32 + col;
    int fx = fl & 7;
#pragma unroll
    for (int kg = 0; kg < 4; ++kg) {
      int gs = (2 * kg + hf) ^ fx;
      tHf[kg] = *(const short8*)&tHs[fl * 64 + gs * 8];
      tLf[kg] = *(const short8*)&tLs[fl * 64 + gs * 8];
    }
    f32x16 aR, aI;
#pragma unroll
    for (int i = 0; i < 16; ++i) { aR[i] = 0.f; aI[i] = 0.f; }
    aR = MFMA32(tHf[0], sHf[0], aR); aR = MFMA32(tHf[0], sLf[0], aR); aR = MFMA32(tLf[0], sHf[0], aR);
    aR = MFMA32(tHf[1], sHf[1], aR); aR = MFMA32(tHf[1], sLf[1], aR); aR = MFMA32(tLf[1], sHf[1], aR);
    aR = MFMA32(tHf[2], nH2,    aR); aR = MFMA32(tHf[2], nL2,    aR); aR = MFMA32(tLf[2], nH2,    aR);
    aR = MFMA32(tHf[3], nH3,    aR); aR = MFMA32(tHf[3], nL3,    aR); aR = MFMA32(tLf[3], nH3,    aR);
    aI = MFMA32(tHf[0], sHf[2], aI); aI = MFMA32(tHf[0], sLf[2], aI); aI = MFMA32(tLf[0], sHf[2], aI);
    aI = MFMA32(tHf[1], sHf[3], aI); aI = MFMA32(tHf[1], sLf[3], aI); aI = MFMA32(tLf[1], sHf[3], aI);
    aI = MFMA32(tHf[2], sHf[0], aI); aI = MFMA32(tHf[2], sLf[0], aI); aI = MFMA32(tLf[2], sHf[0], aI);
    aI = MFMA32(tHf[3], sHf[1], aI); aI = MFMA32(tHf[3], sLf[1], aI); aI = MFMA32(tLf[3], sHf[1], aI);
    // epilogue: D col=lane&31 (pix), row=(reg&3)+8*(reg>>2)+4*(lane>>5)
#pragma unroll
    for (int r = 0; r < 16; ++r) {
      int row = (r & 3) + 8 * (r >> 2) + 4 * hf;
      int fo = ft * 32 + row;                   // local f index in [0,64)
      float vr = aR[r], vi = aI[r];
      float mag2 = fmaf(vr, vr, vi * vi);
      float ln = (__logf(mag2 + EPSF) + sBias[fo]) * INV_STD;
      float inv = sInv[fo];
      size_t fg = (size_t)(b * 128 + f0 + fo);
      __builtin_nontemporal_store(ln, out + fg * WHN + pix);
      __builtin_nontemporal_store(vr * inv, outF + (fg * 2) * WHN + pix);
      __builtin_nontemporal_store(vi * inv, outF + (fg * 2 + 1) * WHN + pix);
    }
  }
}

extern "C" void kernel_launch(void* const* d_in, const int* in_sizes, int n_in,
                              void* d_out, int out_size, void* d_ws, size_t ws_size,
                              hipStream_t stream) {
  const float* ms = (const float*)d_in[0];
  const float* t  = (const float*)d_in[1];
  const float* fr = (const float*)d_in[2];
  const float* bt = (const float*)d_in[3];
  float* out = (float*)d_out;
  float* ws = (float*)d_ws;
  float* wsM = ws;
  float* wsA = ws + 8192;
  float* wsc = ws + 16384;
  float* wsinv = ws + 16640;
  float* wsbias = ws + 17664;
  float* part = ws + 18688;
  size_t need = ((size_t)18688 + (size_t)576 * 2048) * 4;
  int use_part = (ws_size >= need) ? 1 : 0;

  if (use_part) {
    hipLaunchKernelGGL(k_gram, dim3(72, 8), dim3(256), 0, stream, ms, wsM, wsA, part, 1);
    hipLaunchKernelGGL(k_mid, dim3(64), dim3(256), 0, stream, part, wsM, wsA, wsc, out);
  } else {
    hipMemsetAsync(ws, 0, 16384 * sizeof(float), stream);
    hipLaunchKernelGGL(k_gram, dim3(72, 8), dim3(256), 0, stream, ms, wsM, wsA, part, 0);
    hipLaunchKernelGGL(k_cfromM, dim3(1), dim3(256), 0, stream, wsM, wsc, out);
  }
  hipLaunchKernelGGL(k_fnb, dim3(1032), dim3(64), 0, stream, t, fr, bt, wsM, wsA, wsc, wsinv, wsbias, out);
  hipLaunchKernelGGL(k_main, dim3(72, 8, 2), dim3(256), 0, stream, ms, t, wsc, wsinv, wsbias, out);
}

// Round 5
// 167.240 us; speedup vs baseline: 1.0259x; 1.0259x over previous
//
#include <hip/hip_runtime.h>
#include <hip/hip_bf16.h>
#include <math.h>

#define WHN 9216
#define PN 32
#define FN 128
#define BN 8
#define EPSF 1e-8f
#define INV_STD 0.23809523809f   // 1/4.2
#define AUX_IDX 28311552         // 8*128*9216 + 8*128*2*9216

typedef __attribute__((ext_vector_type(8))) short short8;
typedef __attribute__((ext_vector_type(16))) float f32x16;

__device__ __forceinline__ unsigned short bfbits(__hip_bfloat16 h) {
  return *reinterpret_cast<unsigned short*>(&h);
}

// split v into hi/lo bf16 (RNE both); returns packed (lo<<16)|hi
__device__ __forceinline__ unsigned int bfsplit_pk(float v) {
  __hip_bfloat16 h = __float2bfloat16(v);
  unsigned int hs = bfbits(h);
  float r = v - __bfloat162float(h);
  unsigned int ls = bfbits(__float2bfloat16(r));
  return hs | (ls << 16);
}

// ---------------- K1: Gram partials (or atomic fallback) ----------------
// grid (72, 8), block 256. Each block: 128 pixels of one batch.
__global__ __launch_bounds__(256) void k_gram(const float* __restrict__ ms,
                                              float* __restrict__ wsM,
                                              float* __restrict__ wsA,
                                              float* __restrict__ part,
                                              int use_part) {
  const int b = blockIdx.y;
  const int chunk = blockIdx.x;
  const int tid = threadIdx.x;
  __shared__ float4 sA[32][32];
  __shared__ float4 sB[32][32];
  __shared__ float pbuf[2][2048];
  const float4* ms4 = (const float4*)ms;
#pragma unroll
  for (int k = 0; k < 4; ++k) {
    int i4 = tid + k * 256;
    int xq = i4 & 31, p = i4 >> 5;
    sA[xq][p ^ xq] = ms4[((b * 2 + 0) * 32 + p) * 2304 + chunk * 32 + xq];
    sB[xq][p ^ xq] = ms4[((b * 2 + 1) * 32 + p) * 2304 + chunk * 32 + xq];
  }
  __syncthreads();
  const int w = tid >> 6, lane = tid & 63;
  const int pg = lane & 7, qg = lane >> 3;
  float accM[4][4] = {{0}}, accA[4][4] = {{0}};
  for (int xq = w; xq < 32; xq += 4) {
    float4 pa[4], pb[4], qa[4], qb[4];
#pragma unroll
    for (int j = 0; j < 4; ++j) {
      pa[j] = sA[xq][(pg + 8 * j) ^ xq];
      pb[j] = sB[xq][(pg + 8 * j) ^ xq];
      qa[j] = sA[xq][(qg + 8 * j) ^ xq];
      qb[j] = sB[xq][(qg + 8 * j) ^ xq];
    }
#pragma unroll
    for (int j = 0; j < 4; ++j)
#pragma unroll
      for (int k = 0; k < 4; ++k) {
        accM[j][k] += pa[j].x * qa[k].x + pb[j].x * qb[k].x
                    + pa[j].y * qa[k].y + pb[j].y * qb[k].y
                    + pa[j].z * qa[k].z + pb[j].z * qb[k].z
                    + pa[j].w * qa[k].w + pb[j].w * qb[k].w;
        accA[j][k] += pa[j].x * qb[k].x - pb[j].x * qa[k].x
                    + pa[j].y * qb[k].y - pb[j].y * qa[k].y
                    + pa[j].z * qb[k].z - pb[j].z * qa[k].z
                    + pa[j].w * qb[k].w - pb[j].w * qa[k].w;
      }
  }
  if (w < 2) {
#pragma unroll
    for (int j = 0; j < 4; ++j)
#pragma unroll
      for (int k = 0; k < 4; ++k) {
        pbuf[w][lane * 32 + j * 4 + k] = accM[j][k];
        pbuf[w][lane * 32 + 16 + j * 4 + k] = accA[j][k];
      }
  }
  __syncthreads();
  if (w >= 2) {
#pragma unroll
    for (int j = 0; j < 4; ++j)
#pragma unroll
      for (int k = 0; k < 4; ++k) {
        pbuf[w - 2][lane * 32 + j * 4 + k] += accM[j][k];
        pbuf[w - 2][lane * 32 + 16 + j * 4 + k] += accA[j][k];
      }
  }
  __syncthreads();
  for (int idx = tid; idx < 2048; idx += 256) {
    float v = pbuf[0][idx] + pbuf[1][idx];
    if (use_part) {
      part[((size_t)(b * 72 + chunk)) * 2048 + idx] = v;
    } else {
      int lane2 = idx >> 5, r = idx & 31;
      int mat = r >> 4, rr = r & 15, j = rr >> 2, k = rr & 3;
      int p = (lane2 & 7) + 8 * j, q = (lane2 >> 3) + 8 * k;
      float* dst = mat ? wsA : wsM;
      atomicAdd(dst + (b << 10) + p * 32 + q, v);
    }
  }
}

// ---------------- K1b: reduce partials -> M, A, c; zero aux slot ------------
__global__ __launch_bounds__(256) void k_mid(const float* __restrict__ part,
                                             float* __restrict__ wsM,
                                             float* __restrict__ wsA,
                                             float* __restrict__ wsc,
                                             float* __restrict__ out) {
  int g = blockIdx.x * 256 + threadIdx.x;
  if (g == 0) out[AUX_IDX] = 0.f;
  int b = g >> 11, idx = g & 2047;
  const float* p = part + ((size_t)b * 72) * 2048 + idx;
  float s = 0.f;
#pragma unroll 8
  for (int c = 0; c < 72; ++c) s += p[(size_t)c * 2048];
  int lane2 = idx >> 5, r = idx & 31;
  int mat = r >> 4, rr = r & 15, j = rr >> 2, k = rr & 3;
  int pp = (lane2 & 7) + 8 * j, q = (lane2 >> 3) + 8 * k;
  (mat ? wsA : wsM)[(b << 10) + pp * 32 + q] = s;
  if (!mat && pp == q) wsc[(b << 5) + pp] = (1.0f / 32.0f) / (sqrtf(s) + EPSF);
}

// ---------------- c from M diag (atomic fallback path only) ----------------
__global__ void k_cfromM(const float* __restrict__ wsM, float* __restrict__ wsc,
                         float* __restrict__ out) {
  int tid = threadIdx.x;
  if (tid == 0) out[AUX_IDX] = 0.f;
  int b = tid >> 5, p = tid & 31;
  float m = wsM[(b << 10) + p * 33];
  wsc[tid] = (1.0f / 32.0f) / (sqrtf(m) + EPSF);
}

// -------- K2: fnorm (blk<1024) | aux (1024..1031) | T-panel prep (1032..1039)
__global__ __launch_bounds__(64) void k_fnb(const float* __restrict__ t,
                                            const float* __restrict__ freqs,
                                            const float* __restrict__ btab,
                                            const float* __restrict__ wsM,
                                            const float* __restrict__ wsA,
                                            const float* __restrict__ wsc,
                                            float* __restrict__ wsinv,
                                            float* __restrict__ wsbias,
                                            short* __restrict__ wsT,
                                            float* __restrict__ out) {
  const int lane = threadIdx.x;
  if (blockIdx.x >= 1032) {
    // ---- T-panel prep: c_p-scaled, hi/lo bf16, pre-swizzled ----
    const int b = blockIdx.x - 1032;
    __shared__ float sc[32];
    if (lane < 32) sc[lane] = wsc[b * 32 + lane];
    __syncthreads();
    short* dstH = wsT + (size_t)b * 16384;
    short* dstL = dstH + 8192;
#pragma unroll 2
    for (int it = 0; it < 16; ++it) {
      int slot = it * 64 + lane;              // (f, k-group)
      int fl = slot >> 3, g = slot & 7;
      const float* src = t + ((size_t)(b * 128 + fl) * 2 + (g >> 2)) * 32 + (g & 3) * 8;
      int gs = g ^ (fl & 7);
      short8 hv, lv;
#pragma unroll
      for (int e = 0; e < 8; ++e) {
        unsigned int pk = bfsplit_pk(src[e] * sc[(g & 3) * 8 + e]);
        hv[e] = (short)(pk & 0xFFFFu);
        lv[e] = (short)(pk >> 16);
      }
      *(short8*)&dstH[fl * 64 + gs * 8] = hv;
      *(short8*)&dstL[fl * 64 + gs * 8] = lv;
    }
    return;
  }
  if (blockIdx.x >= 1024) {
    // ---- aux scalar ----
    const int b = blockIdx.x - 1024;
    const int p = lane & 31, comp = lane >> 5;
    float acc = 0.f;
#pragma unroll 4
    for (int f = 0; f < FN; ++f) {
      float v = t[((size_t)(b * FN + f) * 2 + comp) * PN + p];
      acc = fmaf(v, v, acc);
    }
    acc += __shfl_xor(acc, 32);
    float val = logf(sqrtf(acc) + 1.0f);
#pragma unroll
    for (int off = 1; off <= 16; off <<= 1) val += __shfl_xor(val, off);
    if (lane == 0) atomicAdd(out + AUX_IDX, val * (1.0f / 256.0f));
    return;
  }
  const int bf = blockIdx.x;
  const int b = bf >> 7;
  __shared__ float tt[64];
  {
    int p = lane & 31, comp = lane >> 5;
    tt[lane] = t[(bf * 2 + comp) * PN + p] * wsc[(b << 5) + p];
  }
  __syncthreads();
  const int pp = lane & 31, qh = lane >> 5;
  const float* Mrow = wsM + (b << 10) + pp * 32 + qh * 16;
  const float* Arow = wsA + (b << 10) + pp * 32 + qh * 16;
  float ap = tt[pp], bp = tt[32 + pp];
  float S = 0.f;
#pragma unroll
  for (int k = 0; k < 16; ++k) {
    int q = qh * 16 + k;
    float aq = tt[q], bq = tt[32 + q];
    S += (ap * aq + bp * bq) * Mrow[k] + 2.0f * (bp * aq) * Arow[k];
  }
#pragma unroll
  for (int off = 32; off; off >>= 1) S += __shfl_xor(S, off);
  if (lane == 0) {
    float fn = sqrtf(fmaxf(S, 1.1920929e-7f));
    wsinv[bf] = 1.0f / fn;
    float x = freqs[bf];
    float idx = (x + 1.0f) * 0.5f * 249.0f;
    idx = fminf(fmaxf(idx, 0.0f), 249.0f);
    float fi = floorf(idx);
    int i0 = (int)fi;
    int i1 = min(i0 + 1, 249);
    float wvv = idx - fi;
    wsbias[bf] = btab[i0] * (1.0f - wvv) + btab[i1] * wvv;
  }
}

// ---------------- K3: main fused pass (split-bf16 MFMA), z-split x2 --------
// grid (72, 8, 2), block 256 = 4 waves; wave -> 32-px strip, 64 f per block.
#define MFMA32(A, B, C) __builtin_amdgcn_mfma_f32_32x32x16_bf16(A, B, C, 0, 0, 0)
__global__ __launch_bounds__(256, 2) void k_main(const float* __restrict__ ms,
                                                 const short* __restrict__ wsT,
                                                 const float* __restrict__ wsinv,
                                                 const float* __restrict__ wsbias,
                                                 float* __restrict__ out) {
  __shared__ short tHs[4096];   // [64 f][64 k], k-group XOR-swizzled
  __shared__ short tLs[4096];
  __shared__ float sInv[64], sBias[64];
  const int b = blockIdx.y;
  const int z = blockIdx.z;
  const int tid = threadIdx.x;
  const int lane = tid & 63, wv = tid >> 6;
  const int col = lane & 31, hf = lane >> 5;
  const int pix = blockIdx.x * 128 + wv * 32 + col;
  const int f0 = z * 64;

  // ---- T panel: async global->LDS, 16 x 1KB wave-chunks, zero VALU ----
  {
    const short* gH = wsT + (size_t)b * 16384 + (size_t)z * 4096;
#pragma unroll
    for (int it = 0; it < 4; ++it) {
      int chunk = wv * 4 + it;            // 0..15
      int half = chunk >> 3;              // 0=hi 1=lo
      int off = (chunk & 7) * 512;        // shorts
      const short* g = gH + half * 8192 + off + lane * 8;
      short* l = (half ? tLs : tHs) + off;
      __builtin_amdgcn_global_load_lds(
          (const __attribute__((address_space(1))) unsigned int*)g,
          (__attribute__((address_space(3))) unsigned int*)l, 16, 0, 0);
    }
  }

  // ---- S fragments: raw mode shapes, bf16 hi/lo split (HW cvt) ----
  const float* msb = ms + (size_t)b * 64 * WHN + pix;
  short8 sHf[4], sLf[4];
#pragma unroll
  for (int kg = 0; kg < 4; ++kg) {
#pragma unroll
    for (int j = 0; j < 8; ++j) {
      int k = kg * 16 + hf * 8 + j;
      unsigned int pk = bfsplit_pk(msb[(size_t)k * WHN]);
      sHf[kg][j] = (short)(pk & 0xFFFFu);
      sLf[kg][j] = (short)(pk >> 16);
    }
  }
  short8 msk;
#pragma unroll
  for (int j = 0; j < 8; ++j) msk[j] = (short)0x8000;
  short8 nH2 = sHf[2] ^ msk, nL2 = sLf[2] ^ msk;
  short8 nH3 = sHf[3] ^ msk, nL3 = sLf[3] ^ msk;

  // ---- stage inv/bias ----
  if (tid < 64) sInv[tid] = wsinv[b * 128 + f0 + tid];
  else if (tid < 128) sBias[tid - 64] = wsbias[b * 128 + f0 + (tid - 64)];
  __syncthreads();

  float* outF = out + (size_t)BN * FN * WHN;  // normed_field base

#pragma unroll
  for (int ft = 0; ft < 2; ++ft) {
    short8 tHf[4], tLf[4];
    int fl = ft * 32 + col;
    int fx = fl & 7;
#pragma unroll
    for (int kg = 0; kg < 4; ++kg) {
      int gs = (2 * kg + hf) ^ fx;
      tHf[kg] = *(const short8*)&tHs[fl * 64 + gs * 8];
      tLf[kg] = *(const short8*)&tLs[fl * 64 + gs * 8];
    }
    f32x16 aR, aI;
#pragma unroll
    for (int i = 0; i < 16; ++i) { aR[i] = 0.f; aI[i] = 0.f; }
    aR = MFMA32(tHf[0], sHf[0], aR); aR = MFMA32(tHf[0], sLf[0], aR); aR = MFMA32(tLf[0], sHf[0], aR);
    aR = MFMA32(tHf[1], sHf[1], aR); aR = MFMA32(tHf[1], sLf[1], aR); aR = MFMA32(tLf[1], sHf[1], aR);
    aR = MFMA32(tHf[2], nH2,    aR); aR = MFMA32(tHf[2], nL2,    aR); aR = MFMA32(tLf[2], nH2,    aR);
    aR = MFMA32(tHf[3], nH3,    aR); aR = MFMA32(tHf[3], nL3,    aR); aR = MFMA32(tLf[3], nH3,    aR);
    aI = MFMA32(tHf[0], sHf[2], aI); aI = MFMA32(tHf[0], sLf[2], aI); aI = MFMA32(tLf[0], sHf[2], aI);
    aI = MFMA32(tHf[1], sHf[3], aI); aI = MFMA32(tHf[1], sLf[3], aI); aI = MFMA32(tLf[1], sHf[3], aI);
    aI = MFMA32(tHf[2], sHf[0], aI); aI = MFMA32(tHf[2], sLf[0], aI); aI = MFMA32(tLf[2], sHf[0], aI);
    aI = MFMA32(tHf[3], sHf[1], aI); aI = MFMA32(tHf[3], sLf[1], aI); aI = MFMA32(tLf[3], sHf[1], aI);
    // epilogue: D col=lane&31 (pix), row=(reg&3)+8*(reg>>2)+4*(lane>>5)
#pragma unroll
    for (int r = 0; r < 16; ++r) {
      int row = (r & 3) + 8 * (r >> 2) + 4 * hf;
      int fo = ft * 32 + row;                   // local f index in [0,64)
      float vr = aR[r], vi = aI[r];
      float mag2 = fmaf(vr, vr, vi * vi);
      float ln = (__logf(mag2 + EPSF) + sBias[fo]) * INV_STD;
      float inv = sInv[fo];
      size_t fg = (size_t)(b * 128 + f0 + fo);
      __builtin_nontemporal_store(ln, out + fg * WHN + pix);
      __builtin_nontemporal_store(vr * inv, outF + (fg * 2) * WHN + pix);
      __builtin_nontemporal_store(vi * inv, outF + (fg * 2 + 1) * WHN + pix);
    }
  }
}

extern "C" void kernel_launch(void* const* d_in, const int* in_sizes, int n_in,
                              void* d_out, int out_size, void* d_ws, size_t ws_size,
                              hipStream_t stream) {
  const float* ms = (const float*)d_in[0];
  const float* t  = (const float*)d_in[1];
  const float* fr = (const float*)d_in[2];
  const float* bt = (const float*)d_in[3];
  float* out = (float*)d_out;
  float* ws = (float*)d_ws;
  float* wsM = ws;
  float* wsA = ws + 8192;
  float* wsc = ws + 16384;
  float* wsinv = ws + 16640;
  float* wsbias = ws + 17664;
  float* part = ws + 18688;
  const size_t PART_FLOATS = (size_t)576 * 2048;
  size_t need = ((size_t)18688 + PART_FLOATS + 65536) * 4;
  int use_part = (ws_size >= need) ? 1 : 0;
  short* wsT = use_part ? (short*)(part + PART_FLOATS) : (short*)(ws + 18688);

  if (use_part) {
    hipLaunchKernelGGL(k_gram, dim3(72, 8), dim3(256), 0, stream, ms, wsM, wsA, part, 1);
    hipLaunchKernelGGL(k_mid, dim3(64), dim3(256), 0, stream, part, wsM, wsA, wsc, out);
  } else {
    (void)hipMemsetAsync(ws, 0, 16384 * sizeof(float), stream);
    hipLaunchKernelGGL(k_gram, dim3(72, 8), dim3(256), 0, stream, ms, wsM, wsA, part, 0);
    hipLaunchKernelGGL(k_cfromM, dim3(1), dim3(256), 0, stream, wsM, wsc, out);
  }
  hipLaunchKernelGGL(k_fnb, dim3(1040), dim3(64), 0, stream, t, fr, bt, wsM, wsA, wsc, wsinv, wsbias, wsT, out);
  hipLaunchKernelGGL(k_main, dim3(72, 8, 2), dim3(256), 0, stream, ms, wsT, wsinv, wsbias, out);
}